// Round 9
// baseline (302.014 us; speedup 1.0000x reference)
//
#include <hip/hip_runtime.h>
#include <stdint.h>

// Ising PT sampler, bit-exact replay of JAX threefry2x32 (partitionable).
// R9: R8 math + wave-neighbor epoch sync instead of per-half-sweep
// __syncthreads. Wave w owns rows 8w..8w+7; before half-update E it spins
// until waves w+-1 have completed E-1 (LDS epoch flags, release/acquire,
// workgroup scope). Covers data dep (E reads parity(E)^1 written at E-1)
// and anti-dep (E writes parity(E), which w+-1's update E-1 reads).

#define LSZ   128
#define NB    16
#define NC    16
#define NSITES (NB*NC*LSZ*LSZ)     // 4194304

// ---------------- threefry2x32 (JAX/Random123, 20 rounds) ----------------
__host__ __device__ __forceinline__ void tf2x32(uint32_t k0, uint32_t k1,
                                                uint32_t x0, uint32_t x1,
                                                uint32_t& o0, uint32_t& o1) {
  uint32_t k2 = k0 ^ k1 ^ 0x1BD11BDAu;
  x0 += k0; x1 += k1;
#define TFR(r) { x0 += x1; x1 = (x1 << (r)) | (x1 >> (32 - (r))); x1 ^= x0; }
  TFR(13) TFR(15) TFR(26) TFR(6)
  x0 += k1; x1 += k2 + 1u;
  TFR(17) TFR(29) TFR(16) TFR(24)
  x0 += k2; x1 += k0 + 2u;
  TFR(13) TFR(15) TFR(26) TFR(6)
  x0 += k0; x1 += k1 + 3u;
  TFR(17) TFR(29) TFR(16) TFR(24)
  x0 += k1; x1 += k2 + 4u;
  TFR(13) TFR(15) TFR(26) TFR(6)
  x0 += k2; x1 += k0 + 5u;
#undef TFR
  o0 = x0; o1 = x1;
}

// dual-block threefry: counters (0,xa),(0,xb), same key; bits = o0^o1.
__device__ __forceinline__ void tf2x32x2(uint32_t k0, uint32_t k1,
                                         uint32_t xa, uint32_t xb,
                                         uint32_t& oa, uint32_t& ob) {
  uint32_t k2 = k0 ^ k1 ^ 0x1BD11BDAu;
  uint32_t a0 = k0, a1 = xa + k1;
  uint32_t b0 = k0, b1 = xb + k1;
#define TFR2(r) { a0 += a1; b0 += b1; \
                  a1 = __builtin_rotateleft32(a1, r); \
                  b1 = __builtin_rotateleft32(b1, r); \
                  a1 ^= a0; b1 ^= b0; }
  TFR2(13) TFR2(15) TFR2(26) TFR2(6)
  a0 += k1; a1 += k2 + 1u; b0 += k1; b1 += k2 + 1u;
  TFR2(17) TFR2(29) TFR2(16) TFR2(24)
  a0 += k2; a1 += k0 + 2u; b0 += k2; b1 += k0 + 2u;
  TFR2(13) TFR2(15) TFR2(26) TFR2(6)
  a0 += k0; a1 += k1 + 3u; b0 += k0; b1 += k1 + 3u;
  TFR2(17) TFR2(29) TFR2(16) TFR2(24)
  a0 += k1; a1 += k2 + 4u; b0 += k1; b1 += k2 + 4u;
  TFR2(13) TFR2(15) TFR2(26) TFR2(6)
  a0 += k2; a1 += k0 + 5u; b0 += k2; b1 += k0 + 5u;
#undef TFR2
  oa = a0 ^ a1;
  ob = b0 ^ b1;
}

__device__ __forceinline__ float tf_uniform(uint32_t w) {
  union { uint32_t u; float f; } cvt;
  cvt.u = (w >> 9) | 0x3f800000u;
  return cvt.f - 1.0f;
}

// signed byte b (compile-time 0..3) of word w
__device__ __forceinline__ int sb(uint32_t w, int b) {
  return (int)((int32_t)(w << ((3 - b) * 8)) >> 24);
}

#define LDS_LD(p)  __hip_atomic_load((p),  __ATOMIC_ACQUIRE, __HIP_MEMORY_SCOPE_WORKGROUP)
#define LDS_ST(p,v) __hip_atomic_store((p), (v), __ATOMIC_RELEASE, __HIP_MEMORY_SCOPE_WORKGROUP)

// ---------------- the fused chunk kernel ----------------
// blockIdx.x = lattice id w. 1024 threads: t>>3 = row, t&7 = 16-col segment.
// Wave v = t>>6 owns rows 8v..8v+7.
__global__ __launch_bounds__(1024) void k_chunk(const float4* __restrict__ in4,
                                                uint32_t* __restrict__ sg,
                                                const float* __restrict__ T,
                                                int* __restrict__ slotmap,
                                                const float* __restrict__ Eprev,
                                                float* __restrict__ Ecur,
                                                float* __restrict__ out,
                                                int chunk, int start, int nsw,
                                                int sample_local, int sidx,
                                                int write_E, int store_back) {
  __shared__ __align__(16) uint32_t lat32[LSZ * LSZ / 4];   // 16 KB
  __shared__ uint32_t kb[5][4];
  __shared__ uint32_t sh_T4, sh_T8;
  __shared__ int sh_bp;
  __shared__ int wred[16];
  __shared__ int wflag[16];

  const int w = blockIdx.x;
  const int t = threadIdx.x;
  const int c = w & 15;
  const int wv = t >> 6;               // wave id 0..15
  const int wm = (wv + 15) & 15;
  const int wp = (wv + 1) & 15;

  // per-sweep keys: fold_in(base, i) then foldlike split -> (black, white)
  if (t < nsw) {
    uint32_t kk0, kk1, a, b;
    tf2x32(0u, 42u, 0u, (uint32_t)(start + t), kk0, kk1);
    tf2x32(kk0, kk1, 0u, 0u, a, b);
    kb[t][0] = a; kb[t][1] = b;
    tf2x32(kk0, kk1, 0u, 1u, a, b);
    kb[t][2] = a; kb[t][3] = b;
  }
  if (t < 16) wflag[t] = 0;

  // lattice load into LDS — band-local: thread t fills its own uint4 (word t)
  if (chunk == 0) {
#pragma unroll
    for (int k = 0; k < 4; ++k) {
      float4 v = in4[(w << 12) + (t << 2) + k];
      lat32[(t << 2) + k] = (v.x >= 0.0f ? 0x01u : 0xFFu)
                          | ((v.y >= 0.0f ? 0x01u : 0xFFu) << 8)
                          | ((v.z >= 0.0f ? 0x01u : 0xFFu) << 16)
                          | ((v.w >= 0.0f ? 0x01u : 0xFFu) << 24);
    }
  } else {
    ((uint4*)lat32)[t] = ((const uint4*)sg)[(w << 10) + t];
  }

  // thread 0: apply previous PT event (chunks >=1), probs, publish
  if (t == 0) {
    int bp;
    if (chunk == 0) {
      bp = w >> 4;
    } else {
      bp = slotmap[w];
      int p = bp >> 1;
      float E0 = Eprev[(2 * p) * NC + c];
      float E1 = Eprev[(2 * p + 1) * NC + c];
      float b0 = 1.0f / T[2 * p];
      float b1 = 1.0f / T[2 * p + 1];
      float d = (b0 - b1) * (E0 - E1);
      uint32_t kk0, kk1, p0, p1, w0, w1;
      tf2x32(0u, 42u, 0u, (uint32_t)(start - 1), kk0, kk1);  // fold_in(base,i)
      tf2x32(kk0, kk1, 0u, 123u, p0, p1);                    // fold_in(k,123)
      tf2x32(p0, p1, 0u, (uint32_t)(p * NC + c), w0, w1);    // uniform elem
      float u = tf_uniform(w0 ^ w1);
      float pa = (d < 0.0f) ? (float)exp((double)d) : 1.0f;
      if (u < pa) bp ^= 1;
    }
    slotmap[w] = bp;
    sh_bp = bp;
    float Tb = T[bp];
    float p4 = (float)exp((double)(-4.0f / Tb));   // ref: f32 div, f32 exp
    float p8 = (float)exp((double)(-8.0f / Tb));
    // u < p  <=>  (bits>>9) < ceil(p * 2^23), exactly
    sh_T4 = (uint32_t)ceil((double)p4 * 8388608.0);
    sh_T8 = (uint32_t)ceil((double)p8 * 8388608.0);
  }
  __syncthreads();   // the only barrier before the epilogue

  const int bp = sh_bp;
  const uint32_t T4 = sh_T4, T8 = sh_T8;
  const uint32_t TOPEN = 0x00800000u;   // accept-all
  const int r    = t >> 3;          // row 0..127
  const int seg  = t & 7;           // 16-col segment
  const int col0 = seg << 4;
  const uint32_t rowbase = ((uint32_t)((bp << 4) | c) << 14) + ((uint32_t)r << 7);
  const int8_t* latb = (const int8_t*)lat32;
  const int own4 = t;               // uint4 index of own segment == t

  for (int sw = 0; sw < nsw; ++sw) {
    for (int par = 0; par < 2; ++par) {
      const int E = sw * 2 + par;
      if (E) {
        // wait until neighbor waves completed half-update E-1
        while (LDS_LD(&wflag[wm]) < E || LDS_LD(&wflag[wp]) < E) {}
      }
      const uint32_t kk0 = kb[sw][par * 2];
      const uint32_t kk1 = kb[sw][par * 2 + 1];
      const int j0 = (r + par) & 1;

      uint4 cv = ((const uint4*)lat32)[own4];
      uint4 uv = ((const uint4*)lat32)[(((r - 1) & 127) << 3) + seg];
      uint4 dv = ((const uint4*)lat32)[(((r + 1) & 127) << 3) + seg];
      int lfb = latb[(r << 7) + ((col0 - 1) & 127)];
      int rtb = latb[(r << 7) + ((col0 + 16) & 127)];

      uint32_t cw[4] = {cv.x, cv.y, cv.z, cv.w};
      uint32_t uw[4] = {uv.x, uv.y, uv.z, uv.w};
      uint32_t dw[4] = {dv.x, dv.y, dv.z, dv.w};

      uint32_t ext[5];
      ext[0] = (cw[0] << 8) | (uint32_t)(uint8_t)lfb;
      ext[1] = (cw[0] >> 24) | (cw[1] << 8);
      ext[2] = (cw[1] >> 24) | (cw[2] << 8);
      ext[3] = (cw[2] >> 24) | (cw[3] << 8);
      ext[4] = (cw[3] >> 24) | ((uint32_t)(uint8_t)rtb << 8);
      uint32_t Y[5], U[4], D[4];
#pragma unroll
      for (int i = 0; i < 4; ++i) {
        uint32_t sh = (ext[i] >> 8) | (ext[i + 1] << 24);
        Y[i] = j0 ? sh : ext[i];
        uint32_t su = (uw[i] >> 8) | ((i < 3 ? uw[i + 1] : 0u) << 24);
        U[i] = j0 ? su : uw[i];
        uint32_t sd = (dw[i] >> 8) | ((i < 3 ? dw[i + 1] : 0u) << 24);
        D[i] = j0 ? sd : dw[i];
      }
      Y[4] = j0 ? (ext[4] >> 8) : ext[4];

      const uint32_t mbase = 0xFEu << (8 * j0);
      uint32_t xm[4] = {0u, 0u, 0u, 0u};
      const uint32_t cnt0 = rowbase + (uint32_t)(col0 + j0);
#pragma unroll
      for (int m2 = 0; m2 < 4; ++m2) {
        const int ma = 2 * m2, mb = 2 * m2 + 1;
        int lfa = sb(Y[(2 * ma) >> 2], (2 * ma) & 3);
        int s0a = sb(Y[(2 * ma + 1) >> 2], (2 * ma + 1) & 3);
        int rta = sb(Y[(2 * ma + 2) >> 2], (2 * ma + 2) & 3);
        int upa = sb(U[(2 * ma) >> 2], (2 * ma) & 3);
        int dna = sb(D[(2 * ma) >> 2], (2 * ma) & 3);
        int qa = s0a * (lfa + rta + upa + dna);
        int lfb2 = sb(Y[(2 * mb) >> 2], (2 * mb) & 3);
        int s0b = sb(Y[(2 * mb + 1) >> 2], (2 * mb + 1) & 3);
        int rtb2 = sb(Y[(2 * mb + 2) >> 2], (2 * mb + 2) & 3);
        int upb = sb(U[(2 * mb) >> 2], (2 * mb) & 3);
        int dnb = sb(D[(2 * mb) >> 2], (2 * mb) & 3);
        int qb = s0b * (lfb2 + rtb2 + upb + dnb);
        uint32_t wa, wb;
        tf2x32x2(kk0, kk1, cnt0 + 2u * (uint32_t)ma, cnt0 + 2u * (uint32_t)mb,
                 wa, wb);
        uint32_t ta = (qa <= 0) ? TOPEN : (qa == 4 ? T8 : T4);
        uint32_t tb = (qb <= 0) ? TOPEN : (qb == 4 ? T8 : T4);
        if ((wa >> 9) < ta) xm[m2] |= mbase;
        if ((wb >> 9) < tb) xm[m2] |= (mbase << 16);
      }
      uint4 nv;
      nv.x = cw[0] ^ xm[0]; nv.y = cw[1] ^ xm[1];
      nv.z = cw[2] ^ xm[2]; nv.w = cw[3] ^ xm[3];
      ((uint4*)lat32)[own4] = nv;

      // publish completion of half-update E (release orders the ds_writes)
      if ((t & 63) == 0) LDS_ST(&wflag[wv], E + 1);
    }

    if (sw == sample_local) {
      // own segment only; same-wave LDS ordering is handled by the compiler
      uint4 cv = ((const uint4*)lat32)[own4];
      float4* dst = (float4*)out
                  + (((size_t)((bp << 5) + (sidx << 4) + c)) << 12)
                  + (r << 5) + (seg << 2);
      uint32_t wvv[4] = {cv.x, cv.y, cv.z, cv.w};
#pragma unroll
      for (int qd = 0; qd < 4; ++qd) {
        float4 f;
        f.x = (float)sb(wvv[qd], 0); f.y = (float)sb(wvv[qd], 1);
        f.z = (float)sb(wvv[qd], 2); f.w = (float)sb(wvv[qd], 3);
        dst[qd] = f;
      }
    }
  }

  if (write_E) {
    // need down-neighbor wave fully done (reads row r+1 at band edge)
    const int Efin = 2 * nsw;
    while (LDS_LD(&wflag[wp]) < Efin) {}
    uint4 cv = ((const uint4*)lat32)[own4];
    uint4 dv = ((const uint4*)lat32)[(((r + 1) & 127) << 3) + seg];
    int rb = latb[(r << 7) + ((col0 + 16) & 127)];
    uint32_t cw[4] = {cv.x, cv.y, cv.z, cv.w};
    uint32_t dw[4] = {dv.x, dv.y, dv.z, dv.w};
    int psum = 0;
#pragma unroll
    for (int i = 0; i < 16; ++i) {
      int ci = sb(cw[i >> 2], i & 3);
      int di = sb(dw[i >> 2], i & 3);
      int ri = (i < 15) ? sb(cw[(i + 1) >> 2], (i + 1) & 3) : rb;
      psum += ci * (di + ri);
    }
#pragma unroll
    for (int o = 32; o > 0; o >>= 1) psum += __shfl_down(psum, o, 64);
    if ((t & 63) == 0) wred[t >> 6] = psum;
    __syncthreads();
    if (t == 0) {
      int tot = 0;
#pragma unroll
      for (int i = 0; i < 16; ++i) tot += wred[i];
      Ecur[(bp << 4) | c] = -(float)tot;
    }
  }

  if (store_back) {
    ((uint4*)sg)[(w << 10) + t] = ((const uint4*)lat32)[t];
  }
}

// ---------------- host ----------------
extern "C" void kernel_launch(void* const* d_in, const int* in_sizes, int n_in,
                              void* d_out, int out_size, void* d_ws, size_t ws_size,
                              hipStream_t stream) {
  const float* spins_in = (const float*)d_in[0];
  const float* T        = (const float*)d_in[1];
  uint32_t* s   = (uint32_t*)d_ws;                          // 4 MB lattice
  float*  Ea    = (float*)((char*)d_ws + (4u << 20));       // 1 KB
  float*  Eb    = (float*)((char*)d_ws + (4u << 20) + 1024);
  int*  slotmap = (int*)((char*)d_ws + (4u << 20) + 2048);  // 1 KB
  float*  out = (float*)d_out;

  // chunks split at PT events (after sweeps 0,5,10,15); samples after 14,19
  const int starts[5]  = {0, 1, 6, 11, 16};
  const int counts[5]  = {1, 5, 5, 5, 4};
  const int samploc[5] = {-1, -1, -1, 3, 3};
  const int sampidx[5] = {0, 0, 0, 0, 1};
  const int writeE[5]  = {1, 1, 1, 1, 0};
  const int storeB[5]  = {1, 1, 1, 1, 0};

  for (int ch = 0; ch < 5; ++ch) {
    float* Ecur  = (ch & 1) ? Eb : Ea;
    float* Eprev = (ch & 1) ? Ea : Eb;
    k_chunk<<<256, 1024, 0, stream>>>((const float4*)spins_in, s, T, slotmap,
                                      Eprev, Ecur, out,
                                      ch, starts[ch], counts[ch],
                                      samploc[ch], sampidx[ch],
                                      writeE[ch], storeB[ch]);
  }
}

// Round 10
// 284.179 us; speedup vs baseline: 1.0628x; 1.0628x over previous
//
#include <hip/hip_runtime.h>
#include <stdint.h>

// Ising PT sampler, bit-exact replay of JAX threefry2x32 (partitionable).
// R10: exact R8 kernel (best so far, 283 us) + __launch_bounds__(1024, 4).
// Theory: without the min-waves hint the compiler squeezed the kernel to
// 32 VGPRs (max-occupancy target), forcing remat/LDS re-reads in the
// unrolled body. At our real occupancy (1 block/CU = 4 waves/SIMD) 128
// VGPRs/wave are available; telling the allocator so should delete the
// ~1.6x issue-slot inflation seen vs the instruction-count model.

#define LSZ   128
#define NB    16
#define NC    16
#define NSITES (NB*NC*LSZ*LSZ)     // 4194304

// ---------------- threefry2x32 (JAX/Random123, 20 rounds) ----------------
__host__ __device__ __forceinline__ void tf2x32(uint32_t k0, uint32_t k1,
                                                uint32_t x0, uint32_t x1,
                                                uint32_t& o0, uint32_t& o1) {
  uint32_t k2 = k0 ^ k1 ^ 0x1BD11BDAu;
  x0 += k0; x1 += k1;
#define TFR(r) { x0 += x1; x1 = (x1 << (r)) | (x1 >> (32 - (r))); x1 ^= x0; }
  TFR(13) TFR(15) TFR(26) TFR(6)
  x0 += k1; x1 += k2 + 1u;
  TFR(17) TFR(29) TFR(16) TFR(24)
  x0 += k2; x1 += k0 + 2u;
  TFR(13) TFR(15) TFR(26) TFR(6)
  x0 += k0; x1 += k1 + 3u;
  TFR(17) TFR(29) TFR(16) TFR(24)
  x0 += k1; x1 += k2 + 4u;
  TFR(13) TFR(15) TFR(26) TFR(6)
  x0 += k2; x1 += k0 + 5u;
#undef TFR
  o0 = x0; o1 = x1;
}

// dual-block threefry: counters (0,xa),(0,xb), same key; bits = o0^o1.
__device__ __forceinline__ void tf2x32x2(uint32_t k0, uint32_t k1,
                                         uint32_t xa, uint32_t xb,
                                         uint32_t& oa, uint32_t& ob) {
  uint32_t k2 = k0 ^ k1 ^ 0x1BD11BDAu;
  uint32_t a0 = k0, a1 = xa + k1;
  uint32_t b0 = k0, b1 = xb + k1;
#define TFR2(r) { a0 += a1; b0 += b1; \
                  a1 = __builtin_rotateleft32(a1, r); \
                  b1 = __builtin_rotateleft32(b1, r); \
                  a1 ^= a0; b1 ^= b0; }
  TFR2(13) TFR2(15) TFR2(26) TFR2(6)
  a0 += k1; a1 += k2 + 1u; b0 += k1; b1 += k2 + 1u;
  TFR2(17) TFR2(29) TFR2(16) TFR2(24)
  a0 += k2; a1 += k0 + 2u; b0 += k2; b1 += k0 + 2u;
  TFR2(13) TFR2(15) TFR2(26) TFR2(6)
  a0 += k0; a1 += k1 + 3u; b0 += k0; b1 += k1 + 3u;
  TFR2(17) TFR2(29) TFR2(16) TFR2(24)
  a0 += k1; a1 += k2 + 4u; b0 += k1; b1 += k2 + 4u;
  TFR2(13) TFR2(15) TFR2(26) TFR2(6)
  a0 += k2; a1 += k0 + 5u; b0 += k2; b1 += k0 + 5u;
#undef TFR2
  oa = a0 ^ a1;
  ob = b0 ^ b1;
}

__device__ __forceinline__ float tf_uniform(uint32_t w) {
  union { uint32_t u; float f; } cvt;
  cvt.u = (w >> 9) | 0x3f800000u;
  return cvt.f - 1.0f;
}

// signed byte b (compile-time 0..3) of word w
__device__ __forceinline__ int sb(uint32_t w, int b) {
  return (int)((int32_t)(w << ((3 - b) * 8)) >> 24);
}

// ---------------- the fused chunk kernel ----------------
// blockIdx.x = lattice id w. 1024 threads: t>>3 = row, t&7 = 16-col segment.
__global__ __launch_bounds__(1024, 4) void k_chunk(const float4* __restrict__ in4,
                                                   uint32_t* __restrict__ sg,
                                                   const float* __restrict__ T,
                                                   int* __restrict__ slotmap,
                                                   const float* __restrict__ Eprev,
                                                   float* __restrict__ Ecur,
                                                   float* __restrict__ out,
                                                   int chunk, int start, int nsw,
                                                   int sample_local, int sidx,
                                                   int write_E, int store_back) {
  __shared__ __align__(16) uint32_t lat32[LSZ * LSZ / 4];   // 16 KB
  __shared__ uint32_t kb[5][4];
  __shared__ uint32_t sh_T4, sh_T8;
  __shared__ int sh_bp;
  __shared__ int wred[16];

  const int w = blockIdx.x;
  const int t = threadIdx.x;
  const int c = w & 15;

  // per-sweep keys: fold_in(base, i) then foldlike split -> (black, white)
  if (t < nsw) {
    uint32_t kk0, kk1, a, b;
    tf2x32(0u, 42u, 0u, (uint32_t)(start + t), kk0, kk1);
    tf2x32(kk0, kk1, 0u, 0u, a, b);
    kb[t][0] = a; kb[t][1] = b;
    tf2x32(kk0, kk1, 0u, 1u, a, b);
    kb[t][2] = a; kb[t][3] = b;
  }

  // lattice load into LDS
  if (chunk == 0) {
    for (int k = 0; k < 4; ++k) {
      int idx = k * 1024 + t;                // word index 0..4095
      float4 v = in4[(w << 12) + idx];
      lat32[idx] = (v.x >= 0.0f ? 0x01u : 0xFFu)
                 | ((v.y >= 0.0f ? 0x01u : 0xFFu) << 8)
                 | ((v.z >= 0.0f ? 0x01u : 0xFFu) << 16)
                 | ((v.w >= 0.0f ? 0x01u : 0xFFu) << 24);
    }
  } else {
    ((uint4*)lat32)[t] = ((const uint4*)sg)[(w << 10) + t];
  }

  // thread 0: apply previous PT event (chunks >=1), probs, publish
  if (t == 0) {
    int bp;
    if (chunk == 0) {
      bp = w >> 4;
    } else {
      bp = slotmap[w];
      int p = bp >> 1;
      float E0 = Eprev[(2 * p) * NC + c];
      float E1 = Eprev[(2 * p + 1) * NC + c];
      float b0 = 1.0f / T[2 * p];
      float b1 = 1.0f / T[2 * p + 1];
      float d = (b0 - b1) * (E0 - E1);
      uint32_t kk0, kk1, p0, p1, w0, w1;
      tf2x32(0u, 42u, 0u, (uint32_t)(start - 1), kk0, kk1);  // fold_in(base,i)
      tf2x32(kk0, kk1, 0u, 123u, p0, p1);                    // fold_in(k,123)
      tf2x32(p0, p1, 0u, (uint32_t)(p * NC + c), w0, w1);    // uniform elem
      float u = tf_uniform(w0 ^ w1);
      float pa = (d < 0.0f) ? (float)exp((double)d) : 1.0f;
      if (u < pa) bp ^= 1;
    }
    slotmap[w] = bp;
    sh_bp = bp;
    float Tb = T[bp];
    float p4 = (float)exp((double)(-4.0f / Tb));   // ref: f32 div, f32 exp
    float p8 = (float)exp((double)(-8.0f / Tb));
    // u < p  <=>  (bits>>9) < ceil(p * 2^23), exactly
    sh_T4 = (uint32_t)ceil((double)p4 * 8388608.0);
    sh_T8 = (uint32_t)ceil((double)p8 * 8388608.0);
  }
  __syncthreads();

  const int bp = sh_bp;
  const uint32_t T4 = sh_T4, T8 = sh_T8;
  const uint32_t TOPEN = 0x00800000u;   // accept-all
  const int r    = t >> 3;          // row 0..127
  const int seg  = t & 7;           // 16-col segment
  const int col0 = seg << 4;
  const uint32_t rowbase = ((uint32_t)((bp << 4) | c) << 14) + ((uint32_t)r << 7);
  const int8_t* latb = (const int8_t*)lat32;
  const int own4 = t;               // uint4 index of own segment == t

  for (int sw = 0; sw < nsw; ++sw) {
    for (int par = 0; par < 2; ++par) {
      const uint32_t kk0 = kb[sw][par * 2];
      const uint32_t kk1 = kb[sw][par * 2 + 1];
      const int j0 = (r + par) & 1;

      uint4 cv = ((const uint4*)lat32)[own4];
      uint4 uv = ((const uint4*)lat32)[(((r - 1) & 127) << 3) + seg];
      uint4 dv = ((const uint4*)lat32)[(((r + 1) & 127) << 3) + seg];
      int lfb = latb[(r << 7) + ((col0 - 1) & 127)];
      int rtb = latb[(r << 7) + ((col0 + 16) & 127)];

      uint32_t cw[4] = {cv.x, cv.y, cv.z, cv.w};
      uint32_t uw[4] = {uv.x, uv.y, uv.z, uv.w};
      uint32_t dw[4] = {dv.x, dv.y, dv.z, dv.w};

      uint32_t ext[5];
      ext[0] = (cw[0] << 8) | (uint32_t)(uint8_t)lfb;
      ext[1] = (cw[0] >> 24) | (cw[1] << 8);
      ext[2] = (cw[1] >> 24) | (cw[2] << 8);
      ext[3] = (cw[2] >> 24) | (cw[3] << 8);
      ext[4] = (cw[3] >> 24) | ((uint32_t)(uint8_t)rtb << 8);
      uint32_t Y[5], U[4], D[4];
#pragma unroll
      for (int i = 0; i < 4; ++i) {
        uint32_t sh = (ext[i] >> 8) | (ext[i + 1] << 24);
        Y[i] = j0 ? sh : ext[i];
        uint32_t su = (uw[i] >> 8) | ((i < 3 ? uw[i + 1] : 0u) << 24);
        U[i] = j0 ? su : uw[i];
        uint32_t sd = (dw[i] >> 8) | ((i < 3 ? dw[i + 1] : 0u) << 24);
        D[i] = j0 ? sd : dw[i];
      }
      Y[4] = j0 ? (ext[4] >> 8) : ext[4];

      const uint32_t mbase = 0xFEu << (8 * j0);   // XOR flips 0x01<->0xFF
      uint32_t xm[4] = {0u, 0u, 0u, 0u};
      const uint32_t cnt0 = rowbase + (uint32_t)(col0 + j0);
#pragma unroll
      for (int m2 = 0; m2 < 4; ++m2) {
        const int ma = 2 * m2, mb = 2 * m2 + 1;
        int lfa = sb(Y[(2 * ma) >> 2], (2 * ma) & 3);
        int s0a = sb(Y[(2 * ma + 1) >> 2], (2 * ma + 1) & 3);
        int rta = sb(Y[(2 * ma + 2) >> 2], (2 * ma + 2) & 3);
        int upa = sb(U[(2 * ma) >> 2], (2 * ma) & 3);
        int dna = sb(D[(2 * ma) >> 2], (2 * ma) & 3);
        int qa = s0a * (lfa + rta + upa + dna);
        int lfb2 = sb(Y[(2 * mb) >> 2], (2 * mb) & 3);
        int s0b = sb(Y[(2 * mb + 1) >> 2], (2 * mb + 1) & 3);
        int rtb2 = sb(Y[(2 * mb + 2) >> 2], (2 * mb + 2) & 3);
        int upb = sb(U[(2 * mb) >> 2], (2 * mb) & 3);
        int dnb = sb(D[(2 * mb) >> 2], (2 * mb) & 3);
        int qb = s0b * (lfb2 + rtb2 + upb + dnb);
        uint32_t wa, wb;
        tf2x32x2(kk0, kk1, cnt0 + 2u * (uint32_t)ma, cnt0 + 2u * (uint32_t)mb,
                 wa, wb);
        uint32_t ta = (qa <= 0) ? TOPEN : (qa == 4 ? T8 : T4);
        uint32_t tb = (qb <= 0) ? TOPEN : (qb == 4 ? T8 : T4);
        if ((wa >> 9) < ta) xm[m2] |= mbase;
        if ((wb >> 9) < tb) xm[m2] |= (mbase << 16);
      }
      uint4 nv;
      nv.x = cw[0] ^ xm[0]; nv.y = cw[1] ^ xm[1];
      nv.z = cw[2] ^ xm[2]; nv.w = cw[3] ^ xm[3];
      ((uint4*)lat32)[own4] = nv;
      __syncthreads();
    }

    if (sw == sample_local) {
      // out[bp][sidx*16+c][r][col0..col0+15] as float
      uint4 cv = ((const uint4*)lat32)[own4];
      float4* dst = (float4*)out
                  + (((size_t)((bp << 5) + (sidx << 4) + c)) << 12)
                  + (r << 5) + (seg << 2);
      uint32_t wv[4] = {cv.x, cv.y, cv.z, cv.w};
#pragma unroll
      for (int qd = 0; qd < 4; ++qd) {
        float4 f;
        f.x = (float)sb(wv[qd], 0); f.y = (float)sb(wv[qd], 1);
        f.z = (float)sb(wv[qd], 2); f.w = (float)sb(wv[qd], 3);
        dst[qd] = f;
      }
    }
  }

  if (write_E) {
    // E = -sum s*(down+right), exact integer in f32
    uint4 cv = ((const uint4*)lat32)[own4];
    uint4 dv = ((const uint4*)lat32)[(((r + 1) & 127) << 3) + seg];
    int rb = latb[(r << 7) + ((col0 + 16) & 127)];
    uint32_t cw[4] = {cv.x, cv.y, cv.z, cv.w};
    uint32_t dw[4] = {dv.x, dv.y, dv.z, dv.w};
    int psum = 0;
#pragma unroll
    for (int i = 0; i < 16; ++i) {
      int ci = sb(cw[i >> 2], i & 3);
      int di = sb(dw[i >> 2], i & 3);
      int ri = (i < 15) ? sb(cw[(i + 1) >> 2], (i + 1) & 3) : rb;
      psum += ci * (di + ri);
    }
#pragma unroll
    for (int o = 32; o > 0; o >>= 1) psum += __shfl_down(psum, o, 64);
    if ((t & 63) == 0) wred[t >> 6] = psum;
    __syncthreads();
    if (t == 0) {
      int tot = 0;
#pragma unroll
      for (int i = 0; i < 16; ++i) tot += wred[i];
      Ecur[(bp << 4) | c] = -(float)tot;
    }
  }

  if (store_back) {
    ((uint4*)sg)[(w << 10) + t] = ((const uint4*)lat32)[t];
  }
}

// ---------------- host ----------------
extern "C" void kernel_launch(void* const* d_in, const int* in_sizes, int n_in,
                              void* d_out, int out_size, void* d_ws, size_t ws_size,
                              hipStream_t stream) {
  const float* spins_in = (const float*)d_in[0];
  const float* T        = (const float*)d_in[1];
  uint32_t* s   = (uint32_t*)d_ws;                          // 4 MB lattice
  float*  Ea    = (float*)((char*)d_ws + (4u << 20));       // 1 KB
  float*  Eb    = (float*)((char*)d_ws + (4u << 20) + 1024);
  int*  slotmap = (int*)((char*)d_ws + (4u << 20) + 2048);  // 1 KB
  float*  out = (float*)d_out;

  // chunks split at PT events (after sweeps 0,5,10,15); samples after 14,19
  const int starts[5]  = {0, 1, 6, 11, 16};
  const int counts[5]  = {1, 5, 5, 5, 4};
  const int samploc[5] = {-1, -1, -1, 3, 3};
  const int sampidx[5] = {0, 0, 0, 0, 1};
  const int writeE[5]  = {1, 1, 1, 1, 0};
  const int storeB[5]  = {1, 1, 1, 1, 0};

  for (int ch = 0; ch < 5; ++ch) {
    float* Ecur  = (ch & 1) ? Eb : Ea;
    float* Eprev = (ch & 1) ? Ea : Eb;
    k_chunk<<<256, 1024, 0, stream>>>((const float4*)spins_in, s, T, slotmap,
                                      Eprev, Ecur, out,
                                      ch, starts[ch], counts[ch],
                                      samploc[ch], sampidx[ch],
                                      writeE[ch], storeB[ch]);
  }
}